// Round 8
// baseline (50.158 us; speedup 1.0000x reference)
//
#include <hip/hip_runtime.h>

// Problem constants (match the JAX reference)
constexpr int BATCH      = 256;
constexpr int T          = 100;
constexpr int J          = 32;
constexpr int EDGES      = 101;
constexpr int NBINS      = 100;
constexpr int NPOINTS    = T * J;          // 3200 points per row
constexpr int ROW_FLOATS = NPOINTS * 3;    // 9600 floats per row
constexpr int NREP       = 32;             // histogram replicas (rep = lane&31)
constexpr int NTHREADS   = 1024;           // 16 waves/block, 2 blocks/CU -> 8 waves/SIMD
constexpr int NWAVES     = NTHREADS / 64;
constexpr int PSTRIDE    = 33;             // points-per-timestep stride (+1 pad:
                                           // b64 partner reads stay free 2-way)
constexpr int TMAIN      = 96;             // 3 rounds x 32 half-waves
constexpr float EPSF     = 1e-8f;
constexpr float NTOT     = 102400.0f;      // T*J*J = counts.sum()

// Raw v_sqrt_f32 (~1 ulp) — guess only; exact binning via squared-domain thresholds.
__device__ __forceinline__ float sqrt_approx(float s) {
    float r;
    asm("v_sqrt_f32 %0, %1" : "=v"(r) : "v"(s));
    return r;
}

__global__ __launch_bounds__(NTHREADS, 8)
void jsd_kernel(const float* __restrict__ g1all,
                const float* __restrict__ g2all,
                float* __restrict__ out)
{
#pragma clang fp contract(off)
    // ONE dataset resident at a time (the occupancy lever): 39.6 KB instead of 77.
    __shared__ float2 sxy[T * PSTRIDE];              // 26,400 B
    __shared__ float  szz[T * PSTRIDE];              // 13,200 B
    __shared__ unsigned int hist[2][NREP][EDGES];    // 25,856 B (both ds accumulate here)
    __shared__ float edg[EDGES];
    __shared__ float sqe[EDGES];                     // squared-domain thresholds m_i
    __shared__ float2 SQ2[NBINS];                    // {m_i, m_{i+1}} pairs
    __shared__ float sred[NWAVES];
    __shared__ float sterm[NBINS];
    __shared__ float s_mx, s_invw;

    const int tid = threadIdx.x;
    const int row = blockIdx.x;
    const int hw  = tid >> 5;     // half-wave id in [0,32): owns one timestep/round
    const int a   = tid & 31;     // own point index within the timestep

    const float* g1 = g1all + (size_t)row * ROW_FLOATS;
    const float* g2 = g2all + (size_t)row * ROW_FLOATS;

    auto stage = [&](const float* __restrict__ g) {
        for (int k = tid; k < NPOINTS; k += NTHREADS) {
            const int t = k >> 5, c = k & 31;
            sxy[t * PSTRIDE + c] = make_float2(g[3 * k], g[3 * k + 1]);
            szz[t * PSTRIDE + c] = g[3 * k + 2];
        }
    };

    // Rotation enumeration: lane a vs (a+k)&31, k=1..16 within its timestep.
    // k<16: unordered pair counted once (weight 2); k==16: both sides (weight 1).
    // (x-y)^2 == (y-x)^2 bitwise, so the k==16 duplicate is exact.
    auto passA = [&](float vmax) -> float {
        for (int r = 0; r < TMAIN / 32; ++r) {
            const int b = (r * 32 + hw) * PSTRIDE;
            const float2 o = sxy[b + a];
            const float  oz = szz[b + a];
#pragma unroll 4
            for (int k = 1; k <= 16; ++k) {
                const int c = b + ((a + k) & 31);
                const float2 p = sxy[c];
                const float  pz = szz[c];
                float dx = o.x - p.x, dy = o.y - p.y, dz = oz - pz;
                vmax = fmaxf(vmax, dx * dx + dy * dy + dz * dz);  // no FMA
            }
        }
#pragma unroll
        for (int j = 0; j < 2; ++j) {       // tail: 4 t x 16 k = 64 items, 2/half-wave
            const int it = hw * 2 + j;
            const int b  = (TMAIN + (it >> 4)) * PSTRIDE;
            const int k  = (it & 15) + 1;
            const float2 o = sxy[b + a];
            const float  oz = szz[b + a];
            const int c = b + ((a + k) & 31);
            const float2 p = sxy[c];
            const float  pz = szz[c];
            float dx = o.x - p.x, dy = o.y - p.y, dz = oz - pz;
            vmax = fmaxf(vmax, dx * dx + dy * dy + dz * dz);
        }
        return vmax;
    };

    auto binOf = [&](float s, float invw) -> int {
        int i = (int)(sqrt_approx(s) * invw);           // guess within +-1 (proven)
        i = i < 0 ? 0 : (i > 99 ? 99 : i);
        float2 tt = SQ2[i];
        i += (s >= tt.y) ? 1 : 0;                       // exclusive with decrement
        i -= (s <  tt.x) ? 1 : 0;
        return i > 99 ? 99 : i;                         // == reference clip
    };

    auto passB = [&](unsigned int* __restrict__ H, float invw) {
        for (int r = 0; r < TMAIN / 32; ++r) {
            const int b = (r * 32 + hw) * PSTRIDE;
            const float2 o = sxy[b + a];
            const float  oz = szz[b + a];
#pragma unroll 4
            for (int k = 1; k <= 16; ++k) {
                const int c = b + ((a + k) & 31);
                const float2 p = sxy[c];
                const float  pz = szz[c];
                float dx = o.x - p.x, dy = o.y - p.y, dz = oz - pz;
                float s  = dx * dx + dy * dy + dz * dz;
                atomicAdd(&H[binOf(s, invw)], (k < 16) ? 2u : 1u);
            }
        }
#pragma unroll
        for (int j = 0; j < 2; ++j) {
            const int it = hw * 2 + j;
            const int b  = (TMAIN + (it >> 4)) * PSTRIDE;
            const int k  = (it & 15) + 1;
            const float2 o = sxy[b + a];
            const float  oz = szz[b + a];
            const int c = b + ((a + k) & 31);
            const float2 p = sxy[c];
            const float  pz = szz[c];
            float dx = o.x - p.x, dy = o.y - p.y, dz = oz - pz;
            float s  = dx * dx + dy * dy + dz * dz;
            atomicAdd(&H[binOf(s, invw)], (k < 16) ? 2u : 1u);
        }
    };

    // ---- Phase 0: zero histograms; stage ds1.
    for (int k = tid; k < 2 * NREP * EDGES; k += NTHREADS)
        (&hist[0][0][0])[k] = 0u;
    stage(g1);
    __syncthreads();

    // ---- Max over ds1, then ds2 (sqrt monotone => sqrt of max).
    float vmax = passA(0.0f);
    __syncthreads();                 // all reads of ds1 done before overwrite
    stage(g2);
    __syncthreads();
    vmax = passA(vmax);

    for (int off = 32; off > 0; off >>= 1)
        vmax = fmaxf(vmax, __shfl_down(vmax, off, 64));
    if ((tid & 63) == 0) sred[tid >> 6] = vmax;
    __syncthreads();
    if (tid == 0) {
        float m = sred[0];
        for (int w = 1; w < NWAVES; ++w) m = fmaxf(m, sred[w]);
        float mx = __fsqrt_rn(m);
        s_mx = mx;
        s_invw = 100.0f / mx;        // guess only — threshold probes are exact
    }
    __syncthreads();
    const float invw = s_invw;

    // edges[i] = mn*w0 + mx*w1, mn == 0 exactly (diagonal pairs) -> mx * w1[i];
    // w1[i] = (float)i * 0.01f, endpoint pinned to 1.0 (validated absmax 0.0).
    if (tid < EDGES) {
        float w1 = (tid == EDGES - 1) ? 1.0f : ((float)tid * 0.01f);
        edg[tid] = s_mx * w1;
    }
    __syncthreads();

    // Squared-domain thresholds: m_i = smallest float y >= 0 with RN(sqrt(y)) >= e[i].
    // Then RN(sqrt(s)) >= e[i] <=> s >= m_i — binning on s EXACTLY reproduces the
    // reference's binning of the RN square-rooted distance (RN-sqrt monotone).
    if (tid < EDGES) {
        float e = edg[tid];
        float y = 0.0f;                              // e[0] == 0 -> m_0 = 0
        if (tid > 0) {
            y = __fmul_rn(e, e);
            for (int it = 0; it < 4 && __fsqrt_rn(y) < e; ++it)
                y = __int_as_float(__float_as_int(y) + 1);   // safety (shouldn't fire)
            for (int it = 0; it < 8; ++it) {
                float py = __int_as_float(__float_as_int(y) - 1);
                if (__fsqrt_rn(py) >= e) y = py; else break;
            }
        }
        sqe[tid] = y;
    }
    __syncthreads();
    if (tid < NBINS) SQ2[tid] = make_float2(sqe[tid], sqe[tid + 1]);
    __syncthreads();

    // ---- Histogram ds2 (still resident), then restage ds1 and histogram it.
    passB(&hist[1][a][0], invw);
    __syncthreads();
    stage(g1);
    __syncthreads();
    passB(&hist[0][a][0], invw);
    __syncthreads();

    // ---- Final: densities + JSD terms; serial 100-add sum (bit-exact).
    if (tid < NBINS) {
        unsigned int c1 = 0, c2 = 0;
        for (int rr = 0; rr < NREP; ++rr) { c1 += hist[0][rr][tid]; c2 += hist[1][rr][tid]; }
        if (tid == 0) { c1 += T * J; c2 += T * J; }  // diagonal zeros -> bin 0

        float w   = edg[tid + 1] - edg[tid];         // jnp.diff(edges)
        float den = __fmul_rn(NTOT, w);
        float px  = __fdiv_rn((float)c1, den);
        float qx  = __fdiv_rn((float)c2, den);
        float m   = (px + qx) * 0.5f;
        float lm  = logf(m + EPSF);
        float term = px * (logf(px + EPSF) - lm) + qx * (logf(qx + EPSF) - lm);
        sterm[tid] = term;
    }
    __syncthreads();
    if (tid == 0) {
        float acc = 0.0f;
        for (int i = 0; i < NBINS; ++i) acc += sterm[i];
        out[row] = acc * 0.5f;
    }
}

extern "C" void kernel_launch(void* const* d_in, const int* in_sizes, int n_in,
                              void* d_out, int out_size, void* d_ws, size_t ws_size,
                              hipStream_t stream) {
    const float* d1 = (const float*)d_in[0];
    const float* d2 = (const float*)d_in[1];
    float* out = (float*)d_out;
    jsd_kernel<<<BATCH, NTHREADS, 0, stream>>>(d1, d2, out);
}